// Round 1
// baseline (223.005 us; speedup 1.0000x reference)
//
#include <hip/hip_runtime.h>
#include <hip/hip_bf16.h>

#define B_ 8
#define L_ 2048
#define D_ 128
#define BL_ (B_ * L_)

// ---------------- Kernel 1: L2 normalize rows ----------------
// context: (B, 2, L, D). One wave per row, 4 rows per 256-block.
__global__ void k_normalize(const float* __restrict__ ctx,
                            float* __restrict__ cn, float* __restrict__ en) {
    int wid  = blockIdx.x * 4 + (threadIdx.x >> 6);   // row id in [0, B*2*L)
    int lane = threadIdx.x & 63;
    int R = B_ * 2 * L_;
    if (wid >= R) return;
    int b   = wid / (2 * L_);
    int rem = wid % (2 * L_);
    int c   = rem / L_;
    int l   = rem % L_;

    const float* src = ctx + (size_t)wid * D_;
    float2 v = ((const float2*)src)[lane];
    float ss = v.x * v.x + v.y * v.y;
    #pragma unroll
    for (int off = 32; off; off >>= 1) ss += __shfl_down(ss, off, 64);
    ss = __shfl(ss, 0, 64);
    float n = fmaxf(sqrtf(ss), 1e-8f);
    float inv = 1.0f / n;
    float* dst = (c == 0 ? cn : en) + (size_t)(b * L_ + l) * D_;
    ((float2*)dst)[lane] = make_float2(v.x * inv, v.y * inv);
}

// ---------------- Kernel 2: f(x) = relu(x@W1+b1)@W2 + b2 for all rows ----------------
// Rows 0..BL-1 = cn rows -> gc ; rows BL..2BL-1 = en rows -> ge.
// W1 staged in LDS; each wave processes 2 rows per iteration.
__global__ __launch_bounds__(256, 2) void k_feval(
        const float* __restrict__ cn, const float* __restrict__ en,
        const float* __restrict__ W1, const float* __restrict__ b1,
        const float* __restrict__ W2, const float* __restrict__ b2,
        float* __restrict__ gc, float* __restrict__ ge) {
    __shared__ float W1s[128 * 128];
    __shared__ float W2s[128];
    __shared__ float b1s[128];
    __shared__ float ybuf[4][2][128];

    int tid = threadIdx.x;
    for (int i = tid; i < (128 * 128) / 4; i += 256)
        ((float4*)W1s)[i] = ((const float4*)W1)[i];
    if (tid < 128) { W2s[tid] = W2[tid]; b1s[tid] = b1[tid]; }
    __syncthreads();

    float bias2 = b2[0];
    int wave = tid >> 6;
    int lane = tid & 63;
    int gw = blockIdx.x * 4 + wave;   // 0..2047 ; 16 rows per wave

    for (int it = 0; it < 8; ++it) {
        int ra = gw * 16 + it * 2;
        int rb = ra + 1;
        const float* rowa = (ra < BL_) ? (cn + (size_t)ra * D_) : (en + (size_t)(ra - BL_) * D_);
        const float* rowb = (rb < BL_) ? (cn + (size_t)rb * D_) : (en + (size_t)(rb - BL_) * D_);
        float2 va = ((const float2*)rowa)[lane];
        float2 vb = ((const float2*)rowb)[lane];
        ybuf[wave][0][2 * lane]     = va.x;
        ybuf[wave][0][2 * lane + 1] = va.y;
        ybuf[wave][1][2 * lane]     = vb.x;
        ybuf[wave][1][2 * lane + 1] = vb.y;
        __syncthreads();

        float a00 = b1s[lane], a01 = b1s[lane + 64];
        float a10 = a00,       a11 = a01;
        #pragma unroll 4
        for (int i = 0; i < 128; ++i) {
            float yi_a = ybuf[wave][0][i];
            float yi_b = ybuf[wave][1][i];
            float w0 = W1s[i * 128 + lane];
            float w1 = W1s[i * 128 + lane + 64];
            a00 = fmaf(yi_a, w0, a00);
            a01 = fmaf(yi_a, w1, a01);
            a10 = fmaf(yi_b, w0, a10);
            a11 = fmaf(yi_b, w1, a11);
        }
        float ta = fmaxf(a00, 0.0f) * W2s[lane] + fmaxf(a01, 0.0f) * W2s[lane + 64];
        float tb = fmaxf(a10, 0.0f) * W2s[lane] + fmaxf(a11, 0.0f) * W2s[lane + 64];
        #pragma unroll
        for (int off = 32; off; off >>= 1) {
            ta += __shfl_down(ta, off, 64);
            tb += __shfl_down(tb, off, 64);
        }
        if (lane == 0) {
            if (ra < BL_) gc[ra] = ta + bias2; else ge[ra - BL_] = ta + bias2;
            if (rb < BL_) gc[rb] = tb + bias2; else ge[rb - BL_] = tb + bias2;
        }
        __syncthreads();
    }
}

// ---------------- Kernel 3: sim = Cn @ En^T, running argmax ----------------
#define BM 128
#define BN 128
#define BK 32
#define LDSTR 132   // padded LDS stride (keeps 16B alignment, breaks pow2 banks)
#define MSPL 4      // m-range splits per batch (each block handles L/MSPL = 512 cols)

__global__ __launch_bounds__(256, 2) void k_simargmax(
        const float* __restrict__ cn, const float* __restrict__ en,
        float* __restrict__ pmax, int* __restrict__ pidx) {
    int b    = blockIdx.y;
    int rb   = blockIdx.x >> 2;    // row block 0..15
    int ms   = blockIdx.x & 3;     // m-split 0..3
    int row0 = rb * BM;
    int m0   = ms * (L_ / MSPL);   // 0,512,1024,1536

    __shared__ float As[BK][LDSTR];
    __shared__ float Bs[BK][LDSTR];
    __shared__ float redv[BM][16];
    __shared__ int   redi[BM][16];

    int tid = threadIdx.x;
    int tx = tid & 15;   // col group
    int ty = tid >> 4;   // row group

    const float* Abase = cn + ((size_t)b * L_ + row0) * D_;
    const float* Bbase = en + ((size_t)b * L_ + m0) * D_;

    float rmax[8];
    int   ridx[8];
    #pragma unroll
    for (int i = 0; i < 8; ++i) { rmax[i] = -3.0e38f; ridx[i] = 0; }

    for (int nt = 0; nt < (L_ / MSPL) / BN; ++nt) {   // 4 n-tiles
        float acc[8][8];
        #pragma unroll
        for (int i = 0; i < 8; ++i)
            #pragma unroll
            for (int j = 0; j < 8; ++j) acc[i][j] = 0.0f;

        for (int kc = 0; kc < D_ / BK; ++kc) {   // 4 k-chunks
            __syncthreads();
            {
                int r  = tid >> 3;          // 0..31
                int kk = (tid & 7) * 4;     // 0,4,...,28
                #pragma unroll
                for (int p = 0; p < 4; ++p) {
                    int rr = r + p * 32;
                    float4 v = *(const float4*)(Abase + (size_t)rr * D_ + kc * BK + kk);
                    As[kk + 0][rr] = v.x; As[kk + 1][rr] = v.y;
                    As[kk + 2][rr] = v.z; As[kk + 3][rr] = v.w;
                    float4 w = *(const float4*)(Bbase + (size_t)(nt * BN + rr) * D_ + kc * BK + kk);
                    Bs[kk + 0][rr] = w.x; Bs[kk + 1][rr] = w.y;
                    Bs[kk + 2][rr] = w.z; Bs[kk + 3][rr] = w.w;
                }
            }
            __syncthreads();
            #pragma unroll
            for (int k = 0; k < BK; ++k) {
                float a[8], bb[8];
                *(float4*)&a[0]  = *(const float4*)&As[k][ty * 8];
                *(float4*)&a[4]  = *(const float4*)&As[k][ty * 8 + 4];
                *(float4*)&bb[0] = *(const float4*)&Bs[k][tx * 8];
                *(float4*)&bb[4] = *(const float4*)&Bs[k][tx * 8 + 4];
                #pragma unroll
                for (int i = 0; i < 8; ++i)
                    #pragma unroll
                    for (int j = 0; j < 8; ++j)
                        acc[i][j] = fmaf(a[i], bb[j], acc[i][j]);
            }
        }
        // running per-thread argmax (m ascending across nt and j -> strict > keeps lowest m)
        #pragma unroll
        for (int i = 0; i < 8; ++i) {
            #pragma unroll
            for (int j = 0; j < 8; ++j) {
                int m = nt * BN + tx * 8 + j;
                if (acc[i][j] > rmax[i]) { rmax[i] = acc[i][j]; ridx[i] = m; }
            }
        }
    }

    __syncthreads();
    #pragma unroll
    for (int i = 0; i < 8; ++i) {
        redv[ty * 8 + i][tx] = rmax[i];
        redi[ty * 8 + i][tx] = ridx[i];
    }
    __syncthreads();
    if (tid < BM) {
        float mv = redv[tid][0];
        int   mi = redi[tid][0];
        #pragma unroll
        for (int t = 1; t < 16; ++t) {
            float v = redv[tid][t];
            int  ix = redi[tid][t];
            if (v > mv || (v == mv && ix < mi)) { mv = v; mi = ix; }
        }
        int row = row0 + tid;
        size_t o = ((size_t)b * L_ + row) * MSPL + ms;
        pmax[o] = mv;
        pidx[o] = mi + m0;
    }
}

// ---------------- Kernel 4: merge splits + output ----------------
__global__ void k_merge(const float* __restrict__ pmax, const int* __restrict__ pidx,
                        const float* __restrict__ gc, const float* __restrict__ ge,
                        float* __restrict__ out) {
    int r = blockIdx.x * 256 + threadIdx.x;
    if (r >= BL_) return;
    float mv = pmax[(size_t)r * MSPL];
    int   mi = pidx[(size_t)r * MSPL];
    #pragma unroll
    for (int s = 1; s < MSPL; ++s) {
        float v = pmax[(size_t)r * MSPL + s];
        int  ix = pidx[(size_t)r * MSPL + s];
        if (v > mv || (v == mv && ix < mi)) { mv = v; mi = ix; }
    }
    int b = r / L_;
    out[r] = gc[r] + ge[(size_t)b * L_ + mi];
}

extern "C" void kernel_launch(void* const* d_in, const int* in_sizes, int n_in,
                              void* d_out, int out_size, void* d_ws, size_t ws_size,
                              hipStream_t stream) {
    const float* context = (const float*)d_in[0];
    const float* W1 = (const float*)d_in[1];
    const float* b1 = (const float*)d_in[2];
    const float* W2 = (const float*)d_in[3];
    const float* b2 = (const float*)d_in[4];
    float* out = (float*)d_out;

    float* ws = (float*)d_ws;
    float* cn   = ws;                           // BL*D
    float* en   = cn + (size_t)BL_ * D_;        // BL*D
    float* gc   = en + (size_t)BL_ * D_;        // BL
    float* ge   = gc + BL_;                     // BL
    float* pmax = ge + BL_;                     // BL*MSPL
    int*   pidx = (int*)(pmax + (size_t)BL_ * MSPL);  // BL*MSPL

    k_normalize<<<(B_ * 2 * L_) / 4, 256, 0, stream>>>(context, cn, en);
    k_feval<<<512, 256, 0, stream>>>(cn, en, W1, b1, W2, b2, gc, ge);
    dim3 g3(16 * MSPL, B_);
    k_simargmax<<<g3, 256, 0, stream>>>(cn, en, pmax, pidx);
    k_merge<<<BL_ / 256, 256, 0, stream>>>(pmax, pidx, gc, ge, out);
}